// Round 2
// baseline (321.290 us; speedup 1.0000x reference)
//
#include <hip/hip_runtime.h>

#define NB 8
#define NN 2048
#define DF 128
#define NF 128

typedef __attribute__((ext_vector_type(8))) __bf16 bf16x8;
typedef __attribute__((ext_vector_type(4))) float f32x4;
typedef __attribute__((ext_vector_type(8))) unsigned short u16x8;
typedef __attribute__((ext_vector_type(4))) unsigned short u16x4;

__device__ inline unsigned short f2bf(float f) {
    unsigned int u = __float_as_uint(f);
    u += 0x7FFFu + ((u >> 16) & 1u);   // round-to-nearest-even
    return (unsigned short)(u >> 16);
}

// K1: colsum (without +1) + copy A -> out.  Grid 8b x 8jt x 16it = 1024 blocks.
__global__ __launch_bounds__(256) void k_colsum_copy(const float* __restrict__ A,
                                                     float* __restrict__ outA,
                                                     float* __restrict__ colsum) {
    int bid = blockIdx.x;
    int it = bid & 15;
    int jt = (bid >> 4) & 7;
    int b  = bid >> 7;
    int t  = threadIdx.x;
    int jq = t & 63;   // float4 column within 256-col tile
    int ir = t >> 6;   // 0..3 row phase
    const float* Ab = A    + (size_t)b * NN * NN;
    float*       Ob = outA + (size_t)b * NN * NN;
    int j = jt * 256 + jq * 4;
    float4 s = make_float4(0.f, 0.f, 0.f, 0.f);
    for (int ii = ir; ii < 128; ii += 4) {
        int i = it * 128 + ii;
        const float4 v = *(const float4*)(Ab + (size_t)i * NN + j);
        *(float4*)(Ob + (size_t)i * NN + j) = v;
        s.x += v.x; s.y += v.y; s.z += v.z; s.w += v.w;
    }
    __shared__ float red[4][256];
    *(float4*)&red[ir][jq * 4] = s;
    __syncthreads();
    float v = red[0][t & 255] + red[1][t & 255] + red[2][t & 255] + red[3][t & 255];
    atomicAdd(colsum + b * NN + jt * 256 + (t & 255), v);
}

// dvec = rsqrt(1 + colsum)
__global__ void k_dvec(const float* __restrict__ colsum, float* __restrict__ dvec) {
    int i = blockIdx.x * 256 + threadIdx.x;   // 16384 total
    dvec[i] = rsqrtf(1.0f + colsum[i]);
}

// XdT[b][f][j] = d[b,j] * X[b,j,f]  (bf16, j-contiguous = MFMA B-operand friendly)
__global__ __launch_bounds__(256) void k_xdt(const float* __restrict__ X,
                                             const float* __restrict__ dvec,
                                             unsigned short* __restrict__ XdT) {
    int bid = blockIdx.x;               // 8192 = 8b x 128f x 8jt
    int jt = bid & 7;
    int f  = (bid >> 3) & 127;
    int b  = bid >> 10;
    int j  = jt * 256 + threadIdx.x;
    float dv = dvec[b * NN + j];
    float x  = X[((size_t)(b * NN + j)) * DF + f];
    XdT[((size_t)b * DF + f) * NN + j] = f2bf(dv * x);
}

// WT[fo][di] = W[di][fo]  (bf16)
__global__ void k_wt(const float* __restrict__ W, unsigned short* __restrict__ WT) {
    int idx = blockIdx.x * 256 + threadIdx.x;  // 16384
    int fo = idx >> 7, di = idx & 127;
    WT[idx] = f2bf(W[di * NF + fo]);
}

// K3: M = (A + I) @ Xd via bf16 MFMA; DADH = d[i] * M, fp32 to ws.
// Grid: 8b x 32 mtiles = 256 blocks, 256 threads (4 waves), tile 64 x 128, BK=64.
__global__ __launch_bounds__(256) void k_gemm1(const float* __restrict__ A,
                                               const unsigned short* __restrict__ XdT,
                                               const float* __restrict__ dvec,
                                               float* __restrict__ DADH) {
    __shared__ unsigned short As[64 * 72];    // pad 64->72: 2-way bank alias only (free)
    __shared__ unsigned short Bs[128 * 72];
    int bid = blockIdx.x;
    int mt = bid & 31;
    int b  = bid >> 5;
    int m0 = mt * 64;
    int t = threadIdx.x;
    int w = t >> 6, l = t & 63, m16 = l & 15, q = l >> 4;
    const float*          Ab = A   + (size_t)b * NN * NN;
    const unsigned short* Xb = XdT + (size_t)b * DF * NN;

    f32x4 acc[8];
#pragma unroll
    for (int c = 0; c < 8; c++) acc[c] = (f32x4){0.f, 0.f, 0.f, 0.f};

    int ti = t >> 3;   // 0..31 (A row / B row-group)
    int tj = t & 7;    // 0..7  (8-elem chunk)

    for (int kk = 0; kk < NN; kk += 64) {
        int kb = kk + tj * 8;
        // global loads first (A fp32, B bf16)
        float4 a0 = *(const float4*)(Ab + (size_t)(m0 + ti) * NN + kb);
        float4 a1 = *(const float4*)(Ab + (size_t)(m0 + ti) * NN + kb + 4);
        float4 a2 = *(const float4*)(Ab + (size_t)(m0 + ti + 32) * NN + kb);
        float4 a3 = *(const float4*)(Ab + (size_t)(m0 + ti + 32) * NN + kb + 4);
        u16x8 b0 = *(const u16x8*)(Xb + (size_t)(ti +  0) * NN + kb);
        u16x8 b1 = *(const u16x8*)(Xb + (size_t)(ti + 32) * NN + kb);
        u16x8 b2 = *(const u16x8*)(Xb + (size_t)(ti + 64) * NN + kb);
        u16x8 b3 = *(const u16x8*)(Xb + (size_t)(ti + 96) * NN + kb);
        __syncthreads();   // previous iter's MFMA reads done before overwrite
        {
            float av0[8] = {a0.x, a0.y, a0.z, a0.w, a1.x, a1.y, a1.z, a1.w};
            float av1[8] = {a2.x, a2.y, a2.z, a2.w, a3.x, a3.y, a3.z, a3.w};
            int g0 = m0 + ti, g1 = m0 + ti + 32;
            u16x8 u0, u1;
#pragma unroll
            for (int c = 0; c < 8; c++) {
                u0[c] = f2bf(av0[c] + ((g0 == kb + c) ? 1.0f : 0.0f));   // +I fused
                u1[c] = f2bf(av1[c] + ((g1 == kb + c) ? 1.0f : 0.0f));
            }
            *(u16x8*)&As[ti * 72 + tj * 8] = u0;
            *(u16x8*)&As[(ti + 32) * 72 + tj * 8] = u1;
        }
        *(u16x8*)&Bs[(ti +  0) * 72 + tj * 8] = b0;
        *(u16x8*)&Bs[(ti + 32) * 72 + tj * 8] = b1;
        *(u16x8*)&Bs[(ti + 64) * 72 + tj * 8] = b2;
        *(u16x8*)&Bs[(ti + 96) * 72 + tj * 8] = b3;
        __syncthreads();
#pragma unroll
        for (int ks = 0; ks < 2; ks++) {
            bf16x8 af = __builtin_bit_cast(bf16x8,
                *(const u16x8*)&As[(w * 16 + m16) * 72 + ks * 32 + q * 8]);
#pragma unroll
            for (int c = 0; c < 8; c++) {
                bf16x8 bf = __builtin_bit_cast(bf16x8,
                    *(const u16x8*)&Bs[(c * 16 + m16) * 72 + ks * 32 + q * 8]);
                acc[c] = __builtin_amdgcn_mfma_f32_16x16x32_bf16(af, bf, acc[c], 0, 0, 0);
            }
        }
    }
    // epilogue: x d[i], write DADH fp32 (quad writes 64B contiguous)
    float dv[4];
#pragma unroll
    for (int r = 0; r < 4; r++) dv[r] = dvec[b * NN + m0 + w * 16 + q * 4 + r];
#pragma unroll
    for (int c = 0; c < 8; c++)
#pragma unroll
        for (int r = 0; r < 4; r++) {
            int grow = m0 + w * 16 + q * 4 + r;
            DADH[((size_t)(b * NN + grow)) * NF + c * 16 + m16] = acc[c][r] * dv[r];
        }
}

// K4: H = relu(DADH @ W) via bf16 MFMA. 256 blocks x 64 rows (flattened 16384 rows).
__global__ __launch_bounds__(256) void k_gemm2(const float* __restrict__ DADH,
                                               const unsigned short* __restrict__ WT,
                                               float* __restrict__ H) {
    __shared__ unsigned short Ds[64 * 136];
    __shared__ unsigned short Ws[128 * 136];
    int bid = blockIdx.x;
    size_t r0 = (size_t)bid * 64;
    int t = threadIdx.x;
    int w = t >> 6, l = t & 63, m16 = l & 15, q = l >> 4;
    {
        int fr = t >> 4;   // 0..15
        int c8 = t & 15;   // 16B chunk, covers 128 cols
#pragma unroll
        for (int p = 0; p < 8; p++) {
            int fo = fr + p * 16;
            *(u16x8*)&Ws[fo * 136 + c8 * 8] = *(const u16x8*)(WT + fo * NF + c8 * 8);
        }
    }
    {
        int rr = t >> 5;   // 0..7
        int c4 = t & 31;   // float4 column: covers 128 cols
#pragma unroll
        for (int p = 0; p < 8; p++) {
            int r = rr + p * 8;   // covers 64 rows
            float4 v = *(const float4*)(DADH + (r0 + r) * DF + c4 * 4);
            u16x4 u;
            u[0] = f2bf(v.x); u[1] = f2bf(v.y); u[2] = f2bf(v.z); u[3] = f2bf(v.w);
            *(u16x4*)&Ds[r * 136 + c4 * 4] = u;
        }
    }
    __syncthreads();
    f32x4 acc[8];
#pragma unroll
    for (int c = 0; c < 8; c++) acc[c] = (f32x4){0.f, 0.f, 0.f, 0.f};
#pragma unroll
    for (int ks = 0; ks < 4; ks++) {
        bf16x8 af = __builtin_bit_cast(bf16x8,
            *(const u16x8*)&Ds[(w * 16 + m16) * 136 + ks * 32 + q * 8]);
#pragma unroll
        for (int c = 0; c < 8; c++) {
            bf16x8 bf = __builtin_bit_cast(bf16x8,
                *(const u16x8*)&Ws[(c * 16 + m16) * 136 + ks * 32 + q * 8]);
            acc[c] = __builtin_amdgcn_mfma_f32_16x16x32_bf16(af, bf, acc[c], 0, 0, 0);
        }
    }
#pragma unroll
    for (int c = 0; c < 8; c++)
#pragma unroll
        for (int r = 0; r < 4; r++) {
            float h = acc[c][r];
            h = h > 0.f ? h : 0.f;
            H[(r0 + w * 16 + q * 4 + r) * NF + c * 16 + m16] = h;
        }
}

extern "C" void kernel_launch(void* const* d_in, const int* in_sizes, int n_in,
                              void* d_out, int out_size, void* d_ws, size_t ws_size,
                              hipStream_t stream) {
    const float* A = (const float*)d_in[0];
    const float* X = (const float*)d_in[1];
    const float* W = (const float*)d_in[2];
    float* out  = (float*)d_out;
    float* outA = out;
    float* H    = out + (size_t)NB * NN * NN;   // tuple: (A, H) flat

    char* ws = (char*)d_ws;
    float* colsum        = (float*)ws;                                   // 64 KB
    float* dvec          = (float*)(ws + 65536);                         // 64 KB
    unsigned short* XdT  = (unsigned short*)(ws + 131072);               // 4 MB
    unsigned short* WT   = (unsigned short*)(ws + 131072 + 4194304);     // 32 KB
    float* DADH          = (float*)(ws + 131072 + 4194304 + 32768);      // 8 MB

    hipMemsetAsync(colsum, 0, 65536, stream);
    k_colsum_copy<<<1024, 256, 0, stream>>>(A, outA, colsum);
    k_dvec<<<64, 256, 0, stream>>>(colsum, dvec);
    k_xdt<<<8192, 256, 0, stream>>>(X, dvec, XdT);
    k_wt<<<64, 256, 0, stream>>>(W, WT);
    k_gemm1<<<256, 256, 0, stream>>>(A, XdT, dvec, DADH);
    k_gemm2<<<256, 256, 0, stream>>>(DADH, WT, H);
}

// Round 3
// 291.898 us; speedup vs baseline: 1.1007x; 1.1007x over previous
//
#include <hip/hip_runtime.h>

#define NB 8
#define NN 2048
#define DF 128
#define NF 128

typedef __attribute__((ext_vector_type(8))) __bf16 bf16x8;
typedef __attribute__((ext_vector_type(4))) float f32x4;
typedef __attribute__((ext_vector_type(8))) unsigned short u16x8;

__device__ inline unsigned short f2bf(float f) {
    unsigned int u = __float_as_uint(f);
    u += 0x7FFFu + ((u >> 16) & 1u);   // round-to-nearest-even
    return (unsigned short)(u >> 16);
}

// K1: colsum of A (pure read). Grid 8b x 8jt x 16it = 1024 blocks.
__global__ __launch_bounds__(256) void k_colsum(const float* __restrict__ A,
                                                float* __restrict__ colsum) {
    int bid = blockIdx.x;
    int it = bid & 15;
    int jt = (bid >> 4) & 7;
    int b  = bid >> 7;
    int t  = threadIdx.x;
    int jq = t & 63;   // float4 column within 256-col tile
    int ir = t >> 6;   // 0..3 row phase
    const float* Ab = A + (size_t)b * NN * NN;
    int j = jt * 256 + jq * 4;
    float4 s = make_float4(0.f, 0.f, 0.f, 0.f);
    for (int ii = ir; ii < 128; ii += 4) {
        int i = it * 128 + ii;
        const float4 v = *(const float4*)(Ab + (size_t)i * NN + j);
        s.x += v.x; s.y += v.y; s.z += v.z; s.w += v.w;
    }
    __shared__ float red[4][256];
    *(float4*)&red[ir][jq * 4] = s;
    __syncthreads();
    float v = red[0][t] + red[1][t] + red[2][t] + red[3][t];
    atomicAdd(colsum + b * NN + jt * 256 + t, v);
}

// K2: XdT[b][f][j] = rsqrt(1+colsum[j]) * X[b,j,f], bf16, j-contiguous.
// Coalesced X row reads + LDS transpose. Grid 8b x 32jt = 256 blocks.
__global__ __launch_bounds__(256) void k_xdt(const float* __restrict__ X,
                                             const float* __restrict__ colsum,
                                             unsigned short* __restrict__ XdT) {
    __shared__ unsigned short T[128 * 72];   // [f][j_local 64->72 pad]
    int jt = blockIdx.x & 31;
    int b  = blockIdx.x >> 5;
    int j0 = jt * 64;
    int t = threadIdx.x;
    int r = t >> 5;        // 8 rows per pass
    int c = t & 31;        // float4 col over 128 feats
#pragma unroll
    for (int p = 0; p < 8; p++) {
        int j = r + p * 8;
        float dv = rsqrtf(1.0f + colsum[b * NN + j0 + j]);
        float4 v = *(const float4*)(X + ((size_t)(b * NN + j0 + j)) * DF + c * 4);
        T[(c * 4 + 0) * 72 + j] = f2bf(v.x * dv);
        T[(c * 4 + 1) * 72 + j] = f2bf(v.y * dv);
        T[(c * 4 + 2) * 72 + j] = f2bf(v.z * dv);
        T[(c * 4 + 3) * 72 + j] = f2bf(v.w * dv);
    }
    __syncthreads();
#pragma unroll
    for (int p = 0; p < 4; p++) {
        int f  = p * 32 + (t >> 3);
        int j8 = (t & 7) * 8;
        u16x8 u = *(const u16x8*)&T[f * 72 + j8];
        *(u16x8*)(XdT + ((size_t)b * DF + f) * NN + j0 + j8) = u;
    }
}

// K3: fused  outA=A copy;  P = d_i*((A+I)@Xd);  H = relu(P@W).
// Grid: 8b x 32 mtiles = 256 blocks, 256 threads, tile 64x128, BK=64.
__global__ __launch_bounds__(256) void k_fused(const float* __restrict__ A,
                                               const unsigned short* __restrict__ XdT,
                                               const float* __restrict__ colsum,
                                               const float* __restrict__ W,
                                               float* __restrict__ outA,
                                               float* __restrict__ H) {
    __shared__ unsigned short As[64 * 72];
    __shared__ unsigned short Bs[128 * 72];
    __shared__ unsigned short Ws[128 * 136];  // [fo][di], di contiguous (B-frag for gemm2)
    __shared__ unsigned short Ps[64 * 136];   // DADH tile bf16 (A-frag for gemm2)
    int bid = blockIdx.x;
    int mt = bid & 31;
    int b  = bid >> 5;
    int m0 = mt * 64;
    int t = threadIdx.x;
    int w = t >> 6, l = t & 63, m16 = l & 15, q = l >> 4;
    const float*          Ab = A    + (size_t)b * NN * NN;
    float*                Ob = outA + (size_t)b * NN * NN;
    const unsigned short* Xb = XdT  + (size_t)b * DF * NN;

    // stage W -> Ws[fo][di] (transpose), bf16; coalesced fp32 reads
    {
        int di8 = t >> 5;          // 0..7
        int fo4 = (t & 31) * 4;    // 0..124
#pragma unroll
        for (int p = 0; p < 16; p++) {
            int di = p * 8 + di8;
            float4 v = *(const float4*)(W + di * NF + fo4);
            Ws[(fo4 + 0) * 136 + di] = f2bf(v.x);
            Ws[(fo4 + 1) * 136 + di] = f2bf(v.y);
            Ws[(fo4 + 2) * 136 + di] = f2bf(v.z);
            Ws[(fo4 + 3) * 136 + di] = f2bf(v.w);
        }
    }

    f32x4 acc[8];
#pragma unroll
    for (int c = 0; c < 8; c++) acc[c] = (f32x4){0.f, 0.f, 0.f, 0.f};

    int ti = t >> 3;   // 0..31
    int tj = t & 7;    // 0..7

    for (int kk = 0; kk < NN; kk += 64) {
        int kb = kk + tj * 8;
        float4 a0 = *(const float4*)(Ab + (size_t)(m0 + ti) * NN + kb);
        float4 a1 = *(const float4*)(Ab + (size_t)(m0 + ti) * NN + kb + 4);
        float4 a2 = *(const float4*)(Ab + (size_t)(m0 + ti + 32) * NN + kb);
        float4 a3 = *(const float4*)(Ab + (size_t)(m0 + ti + 32) * NN + kb + 4);
        u16x8 b0 = *(const u16x8*)(Xb + (size_t)(ti +  0) * NN + kb);
        u16x8 b1 = *(const u16x8*)(Xb + (size_t)(ti + 32) * NN + kb);
        u16x8 b2 = *(const u16x8*)(Xb + (size_t)(ti + 64) * NN + kb);
        u16x8 b3 = *(const u16x8*)(Xb + (size_t)(ti + 96) * NN + kb);
        // A copy-out from registers (same addresses as loads -> coalesced)
        *(float4*)(Ob + (size_t)(m0 + ti) * NN + kb)      = a0;
        *(float4*)(Ob + (size_t)(m0 + ti) * NN + kb + 4)  = a1;
        *(float4*)(Ob + (size_t)(m0 + ti + 32) * NN + kb)     = a2;
        *(float4*)(Ob + (size_t)(m0 + ti + 32) * NN + kb + 4) = a3;
        __syncthreads();   // prev iter's MFMA LDS reads done before overwrite
        {
            float av0[8] = {a0.x, a0.y, a0.z, a0.w, a1.x, a1.y, a1.z, a1.w};
            float av1[8] = {a2.x, a2.y, a2.z, a2.w, a3.x, a3.y, a3.z, a3.w};
            int g0 = m0 + ti, g1 = m0 + ti + 32;
            u16x8 u0, u1;
#pragma unroll
            for (int c = 0; c < 8; c++) {
                u0[c] = f2bf(av0[c] + ((g0 == kb + c) ? 1.0f : 0.0f));   // +I fused
                u1[c] = f2bf(av1[c] + ((g1 == kb + c) ? 1.0f : 0.0f));
            }
            *(u16x8*)&As[ti * 72 + tj * 8] = u0;
            *(u16x8*)&As[(ti + 32) * 72 + tj * 8] = u1;
        }
        *(u16x8*)&Bs[(ti +  0) * 72 + tj * 8] = b0;
        *(u16x8*)&Bs[(ti + 32) * 72 + tj * 8] = b1;
        *(u16x8*)&Bs[(ti + 64) * 72 + tj * 8] = b2;
        *(u16x8*)&Bs[(ti + 96) * 72 + tj * 8] = b3;
        __syncthreads();
#pragma unroll
        for (int ks = 0; ks < 2; ks++) {
            bf16x8 af = __builtin_bit_cast(bf16x8,
                *(const u16x8*)&As[(w * 16 + m16) * 72 + ks * 32 + q * 8]);
#pragma unroll
            for (int c = 0; c < 8; c++) {
                bf16x8 bf = __builtin_bit_cast(bf16x8,
                    *(const u16x8*)&Bs[(c * 16 + m16) * 72 + ks * 32 + q * 8]);
                acc[c] = __builtin_amdgcn_mfma_f32_16x16x32_bf16(af, bf, acc[c], 0, 0, 0);
            }
        }
    }

    // epilogue 1: x d_i, pack to Ps (bf16, C-layout scatter; wave-private rows)
    float dv[4];
#pragma unroll
    for (int r = 0; r < 4; r++)
        dv[r] = rsqrtf(1.0f + colsum[b * NN + m0 + w * 16 + q * 4 + r]);
#pragma unroll
    for (int c = 0; c < 8; c++)
#pragma unroll
        for (int r = 0; r < 4; r++)
            Ps[(w * 16 + q * 4 + r) * 136 + c * 16 + m16] = f2bf(acc[c][r] * dv[r]);
    __syncthreads();   // Ps + Ws visible

    // epilogue 2: H = relu(Ps @ Ws^T)  (Ps: A-frag rows w*16.., Ws: B-frag)
    f32x4 acc2[8];
#pragma unroll
    for (int c = 0; c < 8; c++) acc2[c] = (f32x4){0.f, 0.f, 0.f, 0.f};
#pragma unroll
    for (int ks = 0; ks < 4; ks++) {
        bf16x8 af = __builtin_bit_cast(bf16x8,
            *(const u16x8*)&Ps[(w * 16 + m16) * 136 + ks * 32 + q * 8]);
#pragma unroll
        for (int c = 0; c < 8; c++) {
            bf16x8 bf = __builtin_bit_cast(bf16x8,
                *(const u16x8*)&Ws[(c * 16 + m16) * 136 + ks * 32 + q * 8]);
            acc2[c] = __builtin_amdgcn_mfma_f32_16x16x32_bf16(af, bf, acc2[c], 0, 0, 0);
        }
    }
#pragma unroll
    for (int c = 0; c < 8; c++)
#pragma unroll
        for (int r = 0; r < 4; r++) {
            float h = acc2[c][r];
            h = h > 0.f ? h : 0.f;
            int grow = m0 + w * 16 + q * 4 + r;
            H[((size_t)(b * NN + grow)) * NF + c * 16 + m16] = h;
        }
}

extern "C" void kernel_launch(void* const* d_in, const int* in_sizes, int n_in,
                              void* d_out, int out_size, void* d_ws, size_t ws_size,
                              hipStream_t stream) {
    const float* A = (const float*)d_in[0];
    const float* X = (const float*)d_in[1];
    const float* W = (const float*)d_in[2];
    float* out  = (float*)d_out;
    float* outA = out;
    float* H    = out + (size_t)NB * NN * NN;   // tuple: (A, H) flat

    char* ws = (char*)d_ws;
    float* colsum       = (float*)ws;                 // 64 KB
    unsigned short* XdT = (unsigned short*)(ws + 65536);  // 4 MB

    hipMemsetAsync(colsum, 0, 65536, stream);
    k_colsum<<<1024, 256, 0, stream>>>(A, colsum);
    k_xdt<<<256, 256, 0, stream>>>(X, colsum, XdT);
    k_fused<<<256, 256, 0, stream>>>(A, XdT, colsum, W, outA, H);
}